// Round 2
// baseline (299.656 us; speedup 1.0000x reference)
//
#include <hip/hip_runtime.h>

// ProtoNet: out[q][n] = -|| (xq[q]@W + b) - proto[n] ||^2
// v2b pipeline (v2 + workspace hardening):
//   k_prep : transpose W -> Wt bf16 [512][2048]; bin ys by class
//   k1_csum: per-class support sums (f32)                  -> csum [64][2048]
//   k2p    : proto partials, LDS-tiled, W read once        -> proto_part [8][64][512]
//   k_pfin : sum partials, scale+bias, bf16, full pnorm    -> proto_bf, pnorm
//   k3_gemm: z = xq@W + b, m97 structure (128x128 tile, 4 waves, BK=64,
//            B via global_load_lds w16, A f32->bf16 reg-pack) -> zbuf bf16
//   k5_dist: out = 2*z@proto^T - |z|^2 - |p|^2 (K split over 4 waves, LDS reduce)

typedef __attribute__((ext_vector_type(8))) short short8;
typedef __attribute__((ext_vector_type(4))) float floatx4;

#define S_ROWS 1024
#define F_DIM  2048
#define D_DIM  512
#define NWAY   64
#define Q_ROWS 16384

static __device__ __forceinline__ unsigned short f2bf(float f) {
  unsigned int u = __float_as_uint(f);
  u += 0x7FFF + ((u >> 16) & 1);   // RNE
  return (unsigned short)(u >> 16);
}
static __device__ __forceinline__ float bf2f(unsigned short s) {
  return __uint_as_float(((unsigned int)s) << 16);
}
// pack two floats -> two bf16 (round-half-up; ties-only deviation from RNE)
static __device__ __forceinline__ unsigned int pack_bf2(float x, float y) {
  unsigned int ux = __float_as_uint(x) + 0x8000u;
  unsigned int uy = __float_as_uint(y) + 0x8000u;
  return __builtin_amdgcn_perm(uy, ux, 0x07060302u);  // hi16(uy)<<16 | hi16(ux)
}
// async global->LDS, 16B per lane. LDS dest = wave-uniform base + lane*16.
static __device__ __forceinline__ void load_lds16(const unsigned short* g, unsigned short* l) {
  __builtin_amdgcn_global_load_lds((const __attribute__((address_space(1))) unsigned int*)g,
                                   (__attribute__((address_space(3))) unsigned int*)l,
                                   16, 0, 0);
}

// ---- k_prep: blocks 0..255 transpose W f32 [2048][512] -> Wt bf16 [512][2048];
//      block 256 bins support ids by class ----
__global__ __launch_bounds__(256) void k_prep(const float* __restrict__ W,
                                              unsigned short* __restrict__ Wt,
                                              const int* __restrict__ ys,
                                              int* __restrict__ order,
                                              int* __restrict__ starts,
                                              float* __restrict__ counts) {
  __shared__ unsigned short t[64][65];
  __shared__ int cnt[NWAY];
  __shared__ int st[NWAY + 1];
  __shared__ int wp[NWAY];
  int bx = blockIdx.x;
  int tid = threadIdx.x;
  if (bx < 256) {
    int f0 = (bx >> 3) << 6;   // 32 f-tiles
    int d0 = (bx & 7) << 6;    // 8 d-tiles
    for (int j = 0; j < 16; j++) {
      int lin = j * 256 + tid;
      int fl = lin >> 6, dl = lin & 63;
      t[fl][dl] = f2bf(W[(size_t)(f0 + fl) * D_DIM + d0 + dl]);
    }
    __syncthreads();
    for (int j = 0; j < 16; j++) {
      int lin = j * 256 + tid;
      int dl = lin >> 6, fl = lin & 63;
      Wt[(size_t)(d0 + dl) * F_DIM + f0 + fl] = t[fl][dl];
    }
  } else {
    if (tid < NWAY) cnt[tid] = 0;
    __syncthreads();
    for (int j = tid; j < S_ROWS; j += 256) atomicAdd(&cnt[ys[j]], 1);
    __syncthreads();
    if (tid == 0) {
      int a = 0;
      for (int c = 0; c < NWAY; c++) { st[c] = a; wp[c] = a; a += cnt[c]; }
      st[NWAY] = a;
    }
    __syncthreads();
    for (int j = tid; j < S_ROWS; j += 256) {
      int c = ys[j];
      int p = atomicAdd(&wp[c], 1);
      order[p] = j;
    }
    if (tid < NWAY) counts[tid] = (float)cnt[tid];
    if (tid < NWAY + 1) starts[tid] = st[tid];
  }
}

// ---- K1: class sums. grid = 64 classes x 2 f-tiles; float4 per thread ----
__global__ __launch_bounds__(256) void k1_csum(const float* __restrict__ xs,
                                               const int* __restrict__ order,
                                               const int* __restrict__ starts,
                                               float* __restrict__ csum) {
  __shared__ int lord[S_ROWS];
  int c = blockIdx.x >> 1;
  int tid = threadIdx.x;
  int s = starts[c], e = starts[c + 1];
  int len = e - s;
  for (int j = tid; j < len; j += 256) lord[j] = order[s + j];
  __syncthreads();
  int f0 = (blockIdx.x & 1) * 1024 + tid * 4;
  float4 a = {0.f, 0.f, 0.f, 0.f};
  for (int i = 0; i < len; i++) {
    float4 v = *(const float4*)&xs[(size_t)lord[i] * F_DIM + f0];
    a.x += v.x; a.y += v.y; a.z += v.z; a.w += v.w;
  }
  *(float4*)&csum[(size_t)c * F_DIM + f0] = a;
}

// ---- k2p: proto partials. grid = 8 f-groups x 8 d-chunks = 64 blocks.
//      Each block loops 4 f-subchunks of 64 through LDS, accumulating in regs.
//      W read exactly once across the grid; no atomics. ----
__global__ __launch_bounds__(256) void k2p(const float* __restrict__ W,
                                           const float* __restrict__ csum,
                                           float* __restrict__ proto_part) {
  __shared__ __align__(16) float csl[64 * 65];
  __shared__ __align__(16) float wch[64 * 64];
  int bx = blockIdx.x;
  int fg = bx >> 3, dc = bx & 7;
  int d0 = dc * 64;
  int tid = threadIdx.x;
  int c = tid >> 2, dq = (tid & 3) * 16;
  floatx4 a0 = {0.f,0.f,0.f,0.f}, a1 = a0, a2 = a0, a3 = a0;
  for (int fsub = 0; fsub < 4; fsub++) {
    int f0 = (fg * 4 + fsub) * 64;
    __syncthreads();   // LDS reuse across iterations
    for (int idx = tid; idx < 4096; idx += 256) {
      int r = idx >> 6, q = idx & 63;
      csl[r * 65 + q] = csum[(size_t)r * F_DIM + f0 + q];
      wch[idx] = W[(size_t)(f0 + r) * D_DIM + d0 + q];
    }
    __syncthreads();
#pragma unroll 4
    for (int f = 0; f < 64; f++) {
      float s = csl[c * 65 + f];
      const floatx4* wr = (const floatx4*)&wch[f * 64 + dq];
      floatx4 w0 = wr[0], w1 = wr[1], w2 = wr[2], w3 = wr[3];
      a0 += s * w0; a1 += s * w1; a2 += s * w2; a3 += s * w3;
    }
  }
  float* dst = &proto_part[((size_t)fg * NWAY + c) * D_DIM + d0 + dq];
  *(floatx4*)&dst[0]  = a0;
  *(floatx4*)&dst[4]  = a1;
  *(floatx4*)&dst[8]  = a2;
  *(floatx4*)&dst[12] = a3;
}

// ---- k_pfin: sum 8 partials, scale + bias, bf16 proto, full pnorm[64] ----
__global__ __launch_bounds__(256) void k_pfin(const float* __restrict__ proto_part,
                                              const float* __restrict__ b,
                                              const float* __restrict__ counts,
                                              unsigned short* __restrict__ proto_bf,
                                              float* __restrict__ pnorm) {
  __shared__ float red[256];
  int n = blockIdx.x, tid = threadIdx.x;
  float cntv = counts[n];
  float inv = 1.f / fmaxf(cntv, 1.f);
  float part = 0.f;
#pragma unroll
  for (int h = 0; h < 2; h++) {
    int d = h * 256 + tid;
    float raw = 0.f;
#pragma unroll
    for (int p = 0; p < 8; p++)
      raw += proto_part[((size_t)p * NWAY + n) * D_DIM + d];
    float pv = (raw + cntv * b[d]) * inv;   // cnt==0 -> raw=0, cnt*b=0 -> 0 (matches ref)
    unsigned short hh = f2bf(pv);
    proto_bf[(size_t)n * D_DIM + d] = hh;
    float q = bf2f(hh);
    part += q * q;
  }
  red[tid] = part;
  __syncthreads();
  for (int s = 128; s > 0; s >>= 1) {
    if (tid < s) red[tid] += red[tid + s];
    __syncthreads();
  }
  if (tid == 0) pnorm[n] = red[0];
}

// ---- k3_gemm: z = xq@W + b, bf16 out. m97 structure: 128x128 tile, 4 waves,
//      BK=64, single-buffer LDS, 2 barriers/K-step. grid = 128 m x 4 n = 512. ----
__global__ __launch_bounds__(256) void k3_gemm(const float* __restrict__ xq,
                                               const unsigned short* __restrict__ Wt,
                                               const float* __restrict__ b,
                                               unsigned short* __restrict__ zbuf) {
  __shared__ __align__(16) unsigned short lA[128 * 64];   // 16 KB
  __shared__ __align__(16) unsigned short lB[128 * 64];   // 16 KB
  int tid = threadIdx.x;
  int bx = blockIdx.x;
  // XCD swizzle (512 % 8 == 0, bijective): XCD k gets m-tiles 16k..16k+15;
  // the 4 n-slices of an m-tile are consecutive wgids -> same-XCD L2 reuse of xq.
  int xcd = bx & 7;
  int wg = xcd * 64 + (bx >> 3);
  int mt = wg >> 2;                 // 0..127
  int n0 = (wg & 3) * 128;          // 0..384

  int wave = tid >> 6, lane = tid & 63;
  int wr = wave >> 1, wc = wave & 1;
  int lrow = lane & 15, lquad = lane >> 4;

  const float* Ab = xq + (size_t)mt * 128 * F_DIM;

  floatx4 acc[4][4];
#pragma unroll
  for (int i = 0; i < 4; i++)
#pragma unroll
    for (int j = 0; j < 4; j++) acc[i][j] = (floatx4){0.f, 0.f, 0.f, 0.f};

  // staging decomposition: chunk ch = r*256 + tid -> row = ch>>3 (8 chunks/row),
  // kq = ch&7 (16B each). LDS linear = row-major [row][64 halfs].
  int sr = tid >> 3, skq = tid & 7;
  const float* ag = Ab + (size_t)sr * F_DIM + skq * 8;
  const unsigned short* bg = Wt + (size_t)(n0 + sr) * F_DIM + skq * 8;

  for (int k0 = 0; k0 < F_DIM; k0 += 64) {
    // B: async global->LDS (issue first; DMA overlaps A's VGPR path)
#pragma unroll
    for (int i = 0; i < 4; i++)
      load_lds16(bg + (size_t)i * 32 * F_DIM + k0, &lB[(i * 256 + wave * 64) * 8]);
    // A: f32 global -> regs -> pack bf16 -> chunk-contiguous LDS write
#pragma unroll
    for (int p = 0; p < 4; p++) {
      const float* gp = ag + (size_t)p * 32 * F_DIM + k0;
      float4 v0 = *(const float4*)gp;
      float4 v1 = *(const float4*)(gp + 4);
      uint4 w;
      w.x = pack_bf2(v0.x, v0.y); w.y = pack_bf2(v0.z, v0.w);
      w.z = pack_bf2(v1.x, v1.y); w.w = pack_bf2(v1.z, v1.w);
      *(uint4*)&lA[(p * 256 + tid) * 8] = w;
    }
    __syncthreads();
#pragma unroll
    for (int s = 0; s < 2; s++) {
      short8 af[4], bfr[4];
#pragma unroll
      for (int i = 0; i < 4; i++)
        af[i] = *(const short8*)&lA[(wr * 64 + i * 16 + lrow) * 64 + s * 32 + lquad * 8];
#pragma unroll
      for (int j = 0; j < 4; j++)
        bfr[j] = *(const short8*)&lB[(wc * 64 + j * 16 + lrow) * 64 + s * 32 + lquad * 8];
#pragma unroll
      for (int i = 0; i < 4; i++)
#pragma unroll
        for (int j = 0; j < 4; j++)
          acc[i][j] = __builtin_amdgcn_mfma_f32_16x16x32_bf16(af[i], bfr[j], acc[i][j], 0, 0, 0);
    }
    __syncthreads();
  }

  // epilogue: bias + bf16 store (C layout: col = lane&15, row = lquad*4 + r)
  size_t zr0 = (size_t)mt * 128;
#pragma unroll
  for (int j = 0; j < 4; j++) {
    int col = n0 + wc * 64 + j * 16 + lrow;
    float bb = b[col];
#pragma unroll
    for (int i = 0; i < 4; i++) {
#pragma unroll
      for (int r = 0; r < 4; r++) {
        int row = wr * 64 + i * 16 + lquad * 4 + r;
        zbuf[(zr0 + row) * D_DIM + col] = f2bf(acc[i][j][r] + bb);
      }
    }
  }
}

// ---- k5_dist: out = 2*z@p^T - qn - pn. grid = 256 blocks x 64 q-rows.
//      4 waves each own a 128-wide K-chunk; partials reduced in LDS. ----
__global__ __launch_bounds__(256) void k5_dist(const unsigned short* __restrict__ zbuf,
                                               const unsigned short* __restrict__ proto_bf,
                                               const float* __restrict__ pnorm,
                                               float* __restrict__ out) {
  __shared__ float S[64 * 65];
  __shared__ float qn_l[64];
  __shared__ float pn_l[64];
  int tid = threadIdx.x;
  int q0 = blockIdx.x * 64;
  int wave = tid >> 6, lane = tid & 63;
  int lrow = lane & 15, lquad = lane >> 4;

  for (int i = tid; i < 64 * 65; i += 256) S[i] = 0.f;
  if (tid < 64) { qn_l[tid] = 0.f; pn_l[tid] = pnorm[tid]; }
  __syncthreads();

  floatx4 acc[4][4];
#pragma unroll
  for (int i = 0; i < 4; i++)
#pragma unroll
    for (int j = 0; j < 4; j++) acc[i][j] = (floatx4){0.f, 0.f, 0.f, 0.f};
  float qsq[4] = {0.f, 0.f, 0.f, 0.f};

  int kbase = wave * 128;
#pragma unroll
  for (int kk = 0; kk < 4; kk++) {
    int k0 = kbase + kk * 32;
    short8 af[4], bfr[4];
#pragma unroll
    for (int i = 0; i < 4; i++)
      af[i] = *(const short8*)&zbuf[(size_t)(q0 + i * 16 + lrow) * D_DIM + k0 + lquad * 8];
#pragma unroll
    for (int j = 0; j < 4; j++)
      bfr[j] = *(const short8*)&proto_bf[(size_t)(j * 16 + lrow) * D_DIM + k0 + lquad * 8];
#pragma unroll
    for (int i = 0; i < 4; i++) {
#pragma unroll
      for (int h = 0; h < 8; h++) {
        float v = bf2f((unsigned short)af[i][h]);
        qsq[i] += v * v;
      }
#pragma unroll
      for (int j = 0; j < 4; j++)
        acc[i][j] = __builtin_amdgcn_mfma_f32_16x16x32_bf16(af[i], bfr[j], acc[i][j], 0, 0, 0);
    }
  }

  // qn: reduce over the 4 k-offset lanes (lquad), then over the 4 waves via LDS
#pragma unroll
  for (int i = 0; i < 4; i++) {
    float s = qsq[i];
    s += __shfl_xor(s, 16);
    s += __shfl_xor(s, 32);
    if (lquad == 0) atomicAdd(&qn_l[i * 16 + lrow], s);
  }
  // S: 4 waves hold K-partials of the same 64x64 tile
#pragma unroll
  for (int i = 0; i < 4; i++)
#pragma unroll
    for (int j = 0; j < 4; j++)
#pragma unroll
      for (int r = 0; r < 4; r++)
        atomicAdd(&S[(i * 16 + lquad * 4 + r) * 65 + j * 16 + lrow], acc[i][j][r]);
  __syncthreads();

  int row = tid >> 2, c0 = (tid & 3) * 16;
  float qv = qn_l[row];
#pragma unroll
  for (int u = 0; u < 4; u++) {
    float4 o;
    int cb = c0 + u * 4;
    o.x = 2.f * S[row * 65 + cb + 0] - qv - pn_l[cb + 0];
    o.y = 2.f * S[row * 65 + cb + 1] - qv - pn_l[cb + 1];
    o.z = 2.f * S[row * 65 + cb + 2] - qv - pn_l[cb + 2];
    o.w = 2.f * S[row * 65 + cb + 3] - qv - pn_l[cb + 3];
    *(float4*)&out[(size_t)(q0 + row) * NWAY + cb] = o;
  }
}

extern "C" void kernel_launch(void* const* d_in, const int* in_sizes, int n_in,
                              void* d_out, int out_size, void* d_ws, size_t ws_size,
                              hipStream_t stream) {
  const float* xs = (const float*)d_in[0];
  const int* ys = (const int*)d_in[1];
  const float* xq = (const float*)d_in[2];
  const float* W = (const float*)d_in[3];
  const float* b = (const float*)d_in[4];
  float* out = (float*)d_out;
  char* ws = (char*)d_ws;

  size_t off = 0;
  auto take = [&](size_t bytes) -> char* {
    char* r = ws + off;
    off += (bytes + 255) & ~(size_t)255;
    return r;
  };
  unsigned short* Wt = (unsigned short*)take((size_t)D_DIM * F_DIM * 2);       // 2 MB
  float* csum = (float*)take((size_t)NWAY * F_DIM * 4);                        // 512 KB
  float* proto_part = (float*)take((size_t)8 * NWAY * D_DIM * 4);             // 1 MB
  unsigned short* proto_bf = (unsigned short*)take((size_t)NWAY * D_DIM * 2); // 64 KB
  float* counts = (float*)take(NWAY * 4);
  float* pnorm = (float*)take(NWAY * 4);
  int* order = (int*)take(S_ROWS * 4);
  int* starts = (int*)take((NWAY + 1) * 4);
  unsigned short* zbuf = (unsigned short*)take((size_t)Q_ROWS * D_DIM * 2);   // 16 MB

  // Workspace guard: if ws is too small, fail cleanly (wrong output) rather
  // than corrupt device memory and kill the container.
  if (off > ws_size) return;

  k_prep<<<257, 256, 0, stream>>>(W, Wt, ys, order, starts, counts);
  k1_csum<<<128, 256, 0, stream>>>(xs, order, starts, csum);
  k2p<<<64, 256, 0, stream>>>(W, csum, proto_part);
  k_pfin<<<NWAY, 256, 0, stream>>>(proto_part, b, counts, proto_bf, pnorm);
  k3_gemm<<<512, 256, 0, stream>>>(xq, Wt, b, zbuf);
  k5_dist<<<256, 256, 0, stream>>>(zbuf, proto_bf, pnorm, out);
}